// Round 1
// baseline (169.190 us; speedup 1.0000x reference)
//
#include <hip/hip_runtime.h>
#include <math.h>

// Problem constants (from reference): B=256, T=1024, F=64, Z=32, H=512
#define NB 256
#define NT 1024
#define NF 64
#define NZ 32
#define NH 512

// Key algebraic reduction: reference returns ys[0] == h2 after the FIRST scan
// step (input time index T-1), with zero initial h/c. Therefore:
//   - h @ W_hh.T == 0  -> W_hh1/W_hh2 unused
//   - sigmoid(f)*c == 0 -> f-gate rows unused
//   - c = sigmoid(i)*tanh(g); h = sigmoid(o)*tanh(c)
// Final: out[b] = sum_j h2[b,j]*W_lin[0,j] + b_lin[0]

__device__ __forceinline__ float sigmoidf_(float x) {
    return 1.0f / (1.0f + __expf(-x));
}

// ---------------------------------------------------------------------------
// prep: build xinT[96][256] (transposed activations: feature-major, batch in
// lanes) and initialize out[b] = b_lin[0] (d_out is poisoned before each run).
// ---------------------------------------------------------------------------
__global__ __launch_bounds__(256) void k_prep(
    const float* __restrict__ input, const float* __restrict__ z,
    const float* __restrict__ b_lin, float* __restrict__ xinT,
    float* __restrict__ out)
{
    int idx = blockIdx.x * 256 + threadIdx.x;   // 0 .. 96*256-1
    int k  = idx >> 8;                          // feature 0..95
    int bt = idx & 255;                         // batch
    float v;
    if (k < NF) v = input[(size_t)bt * (NT * NF) + (size_t)(NT - 1) * NF + k];
    else        v = z[bt * NZ + (k - NF)];
    xinT[k * NB + bt] = v;                      // coalesced store
    if (idx < NB) out[idx] = b_lin[0];
}

// ---------------------------------------------------------------------------
// layer 1: h1T[512][256] = lstm_cell(xinT) with h=c=0.
// Grid 128 blocks x 256 thr. lane = batch, wave-uniform weight rows -> s_load.
// blockIdx&3 = batch tile (constant per XCD under x%8 round-robin).
// ---------------------------------------------------------------------------
__global__ __launch_bounds__(256) void k_lstm1(
    const float* __restrict__ W_ih1, const float* __restrict__ b_ih1,
    const float* __restrict__ b_hh1, const float* __restrict__ xinT,
    float* __restrict__ h1T)
{
    const int lane = threadIdx.x & 63;
    const int wv   = __builtin_amdgcn_readfirstlane(threadIdx.x >> 6); // 0..3
    const int btb  = blockIdx.x & 3;
    const int jb   = blockIdx.x >> 2;          // 0..31
    const int bt   = btb * 64 + lane;
    const int j0   = jb * 16 + wv * 4;         // 4 hidden units per wave
    const int K    = NF + NZ;                  // 96

    float acc[4][3];
    #pragma unroll
    for (int jj = 0; jj < 4; ++jj)
        acc[jj][0] = acc[jj][1] = acc[jj][2] = 0.0f;

    const float* __restrict__ wi[4];
    const float* __restrict__ wg[4];
    const float* __restrict__ wo[4];
    #pragma unroll
    for (int jj = 0; jj < 4; ++jj) {
        int j = j0 + jj;
        wi[jj] = W_ih1 + (size_t)j * K;            // i-gate row
        wg[jj] = W_ih1 + (size_t)(1024 + j) * K;   // g-gate row
        wo[jj] = W_ih1 + (size_t)(1536 + j) * K;   // o-gate row
    }

    #pragma unroll 4
    for (int k = 0; k < K; ++k) {
        float h = xinT[k * NB + bt];               // coalesced vector load
        #pragma unroll
        for (int jj = 0; jj < 4; ++jj) {
            acc[jj][0] = fmaf(wi[jj][k], h, acc[jj][0]);  // scalar * vector
            acc[jj][1] = fmaf(wg[jj][k], h, acc[jj][1]);
            acc[jj][2] = fmaf(wo[jj][k], h, acc[jj][2]);
        }
    }

    #pragma unroll
    for (int jj = 0; jj < 4; ++jj) {
        int j = j0 + jj;
        float gi = acc[jj][0] + b_ih1[j]        + b_hh1[j];
        float gg = acc[jj][1] + b_ih1[1024 + j] + b_hh1[1024 + j];
        float go = acc[jj][2] + b_ih1[1536 + j] + b_hh1[1536 + j];
        float c1 = sigmoidf_(gi) * tanhf(gg);
        float h1 = sigmoidf_(go) * tanhf(c1);
        h1T[j * NB + bt] = h1;                     // coalesced store
    }
}

// ---------------------------------------------------------------------------
// layer 2 + final linear: h2 = lstm_cell(h1T) with h=c=0;
// out[bt] += sum_j h2[j,bt] * W_lin[j]  (atomicAdd; out pre-set to b_lin).
// Grid 256 blocks x 256 thr; each wave: 2 hidden units x 3 gates, K=512.
// ---------------------------------------------------------------------------
__global__ __launch_bounds__(256) void k_lstm2(
    const float* __restrict__ W_ih2, const float* __restrict__ b_ih2,
    const float* __restrict__ b_hh2, const float* __restrict__ W_lin,
    const float* __restrict__ h1T, float* __restrict__ out)
{
    const int lane = threadIdx.x & 63;
    const int wv   = __builtin_amdgcn_readfirstlane(threadIdx.x >> 6); // 0..3
    const int btb  = blockIdx.x & 3;
    const int jb   = blockIdx.x >> 2;          // 0..63
    const int bt   = btb * 64 + lane;
    const int j0   = jb * 8 + wv * 2;          // 2 hidden units per wave

    float acc[2][3];
    #pragma unroll
    for (int jj = 0; jj < 2; ++jj)
        acc[jj][0] = acc[jj][1] = acc[jj][2] = 0.0f;

    const float* __restrict__ wi[2];
    const float* __restrict__ wg[2];
    const float* __restrict__ wo[2];
    #pragma unroll
    for (int jj = 0; jj < 2; ++jj) {
        int j = j0 + jj;
        wi[jj] = W_ih2 + (size_t)j * NH;
        wg[jj] = W_ih2 + (size_t)(1024 + j) * NH;
        wo[jj] = W_ih2 + (size_t)(1536 + j) * NH;
    }

    #pragma unroll 8
    for (int k = 0; k < NH; ++k) {
        float h = h1T[k * NB + bt];                // coalesced vector load
        #pragma unroll
        for (int jj = 0; jj < 2; ++jj) {
            acc[jj][0] = fmaf(wi[jj][k], h, acc[jj][0]);
            acc[jj][1] = fmaf(wg[jj][k], h, acc[jj][1]);
            acc[jj][2] = fmaf(wo[jj][k], h, acc[jj][2]);
        }
    }

    float partial = 0.0f;
    #pragma unroll
    for (int jj = 0; jj < 2; ++jj) {
        int j = j0 + jj;
        float gi = acc[jj][0] + b_ih2[j]        + b_hh2[j];
        float gg = acc[jj][1] + b_ih2[1024 + j] + b_hh2[1024 + j];
        float go = acc[jj][2] + b_ih2[1536 + j] + b_hh2[1536 + j];
        float c2 = sigmoidf_(gi) * tanhf(gg);
        float h2 = sigmoidf_(go) * tanhf(c2);
        partial  = fmaf(h2, W_lin[j], partial);
    }
    atomicAdd(out + bt, partial);
}

// ---------------------------------------------------------------------------
extern "C" void kernel_launch(void* const* d_in, const int* in_sizes, int n_in,
                              void* d_out, int out_size, void* d_ws, size_t ws_size,
                              hipStream_t stream) {
    const float* input = (const float*)d_in[0];
    const float* z     = (const float*)d_in[1];
    // d_in[2]=h0, d_in[3]=c0: zeros by construction -> unused
    const float* W_ih1 = (const float*)d_in[4];
    // d_in[5]=W_hh1 unused (h0==0)
    const float* b_ih1 = (const float*)d_in[6];
    const float* b_hh1 = (const float*)d_in[7];
    const float* W_ih2 = (const float*)d_in[8];
    // d_in[9]=W_hh2 unused
    const float* b_ih2 = (const float*)d_in[10];
    const float* b_hh2 = (const float*)d_in[11];
    const float* W_lin = (const float*)d_in[12];
    const float* b_lin = (const float*)d_in[13];

    float* out  = (float*)d_out;        // 256 floats
    float* xinT = (float*)d_ws;         // [96][256]
    float* h1T  = xinT + 96 * NB;       // [512][256]

    k_prep <<< 96, 256, 0, stream>>>(input, z, b_lin, xinT, out);
    k_lstm1<<<128, 256, 0, stream>>>(W_ih1, b_ih1, b_hh1, xinT, h1T);
    k_lstm2<<<256, 256, 0, stream>>>(W_ih2, b_ih2, b_hh2, W_lin, h1T, out);
}

// Round 2
// 144.997 us; speedup vs baseline: 1.1669x; 1.1669x over previous
//
#include <hip/hip_runtime.h>
#include <math.h>

// Problem constants: B=256, T=1024, F=64, Z=32, H=512
#define NB 256
#define NT 1024
#define NF 64
#define NZ 32
#define NH 512

// Algebraic reduction (see round 0): reference returns h2 after the FIRST
// scan step (time index T-1) with zero initial h/c:
//   - W_hh1/W_hh2 and the f-gate are dead
//   - c = sigmoid(i)*tanh(g); h = sigmoid(o)*tanh(c)
//   - out[b] = sum_j h2[b,j]*W_lin[j] + b_lin[0]
//
// Layouts (workspace):
//   xin4: [24][256] float4  — xin[k][b] packed 4-consecutive-k per lane
//   h1p : [128][256] float4 — h1[j][b] packed 4-consecutive-j per lane

__device__ __forceinline__ float sigmoidf_(float x) {
    return 1.0f / (1.0f + __expf(-x));
}

// ---------------------------------------------------------------------------
// prep: build xin4 and init out[b] = b_lin[0].
// grid 96 x 256. block = feature k, thread = batch bt.
// ---------------------------------------------------------------------------
__global__ __launch_bounds__(256) void k_prep(
    const float* __restrict__ input, const float* __restrict__ z,
    const float* __restrict__ b_lin, float* __restrict__ xin4f,
    float* __restrict__ out)
{
    int k  = blockIdx.x;
    int bt = threadIdx.x;
    float v;
    if (k < NF) v = input[(size_t)bt * (NT * NF) + (size_t)(NT - 1) * NF + k];
    else        v = z[bt * NZ + (k - NF)];
    // packed [k>>2][bt][k&3]
    xin4f[(k >> 2) * (NB * 4) + bt * 4 + (k & 3)] = v;
    if (k == 0) out[bt] = b_lin[0];
}

// ---------------------------------------------------------------------------
// layer 1: h1 = lstm_cell(xin) with h=c=0.
// grid 1024 x 64 (1 wave/block): btb = blockIdx>>8 (same-group replicas land
// on the same XCD: x and x+256 are congruent mod 8), group g = blockIdx&255.
// Each wave: 2 hidden units (6 weight rows), K=96 as 24 float4 iters.
// ---------------------------------------------------------------------------
__global__ __launch_bounds__(64) void k_lstm1(
    const float* __restrict__ W_ih1, const float* __restrict__ b_ih1,
    const float* __restrict__ b_hh1, const float* __restrict__ xin4,
    float* __restrict__ h1p)
{
    const int lane = threadIdx.x;
    const int btb  = blockIdx.x >> 8;      // 0..3
    const int g    = blockIdx.x & 255;     // unit-group (2 units)
    const int bt   = btb * 64 + lane;
    const int j0   = 2 * g;
    const int K    = NF + NZ;              // 96

    const float4* __restrict__ xv = (const float4*)xin4 + bt;

    // rows: [u][gate]: gate bases 0 (i), 1024 (g), 1536 (o)
    const float* __restrict__ w[6];
    #pragma unroll
    for (int u = 0; u < 2; ++u) {
        w[u * 3 + 0] = W_ih1 + (size_t)(j0 + u) * K;
        w[u * 3 + 1] = W_ih1 + (size_t)(1024 + j0 + u) * K;
        w[u * 3 + 2] = W_ih1 + (size_t)(1536 + j0 + u) * K;
    }

    float acc[6] = {0, 0, 0, 0, 0, 0};
    #pragma unroll
    for (int k4 = 0; k4 < 24; ++k4) {
        float4 h = xv[k4 * NB];            // coalesced 16B/lane
        #pragma unroll
        for (int r = 0; r < 6; ++r) {
            const float* wr = w[r] + k4 * 4;   // wave-uniform -> s_load
            acc[r] = fmaf(wr[0], h.x, acc[r]);
            acc[r] = fmaf(wr[1], h.y, acc[r]);
            acc[r] = fmaf(wr[2], h.z, acc[r]);
            acc[r] = fmaf(wr[3], h.w, acc[r]);
        }
    }

    float hu[2];
    #pragma unroll
    for (int u = 0; u < 2; ++u) {
        int j = j0 + u;
        float gi = acc[u * 3 + 0] + b_ih1[j]        + b_hh1[j];
        float gg = acc[u * 3 + 1] + b_ih1[1024 + j] + b_hh1[1024 + j];
        float go = acc[u * 3 + 2] + b_ih1[1536 + j] + b_hh1[1536 + j];
        float c1 = sigmoidf_(gi) * tanhf(gg);
        hu[u] = sigmoidf_(go) * tanhf(c1);
    }
    // packed store: float index (j0>>2)*1024 + bt*4 + (j0&3); j0 even -> 8B aligned
    float2 hv = make_float2(hu[0], hu[1]);
    *(float2*)(h1p + (j0 >> 2) * (NB * 4) + bt * 4 + (j0 & 3)) = hv;
}

// ---------------------------------------------------------------------------
// layer 2 + linear: h2 = lstm_cell(h1); out[bt] += h2 . W_lin  (atomic).
// grid 1024 x 256 (4 waves/block, 16 waves/CU): block = (btb = blockIdx>>8,
// group g = blockIdx&255 covering 2 units / 6 rows). Wave wv takes K-chunk
// [wv*128, wv*128+128); partials reduced via LDS; wave 0 does the epilogue.
// ---------------------------------------------------------------------------
__global__ __launch_bounds__(256) void k_lstm2(
    const float* __restrict__ W_ih2, const float* __restrict__ b_ih2,
    const float* __restrict__ b_hh2, const float* __restrict__ W_lin,
    const float* __restrict__ h1p, float* __restrict__ out)
{
    const int tid  = threadIdx.x;
    const int lane = tid & 63;
    const int wv   = __builtin_amdgcn_readfirstlane(tid >> 6); // 0..3
    const int btb  = blockIdx.x >> 8;      // 0..3
    const int g    = blockIdx.x & 255;     // unit-group (2 units)
    const int bt   = btb * 64 + lane;
    const int j0   = 2 * g;

    const float4* __restrict__ hv = (const float4*)h1p + bt;

    const float* __restrict__ w[6];
    #pragma unroll
    for (int u = 0; u < 2; ++u) {
        w[u * 3 + 0] = W_ih2 + (size_t)(j0 + u) * NH;
        w[u * 3 + 1] = W_ih2 + (size_t)(1024 + j0 + u) * NH;
        w[u * 3 + 2] = W_ih2 + (size_t)(1536 + j0 + u) * NH;
    }

    float acc[6] = {0, 0, 0, 0, 0, 0};
    const int k4base = wv * 32;            // 32 float4 iters = 128 K
    #pragma unroll 8
    for (int k4i = 0; k4i < 32; ++k4i) {
        int k4 = k4base + k4i;
        float4 h = hv[k4 * NB];            // coalesced 16B/lane
        #pragma unroll
        for (int r = 0; r < 6; ++r) {
            const float* wr = w[r] + k4 * 4;   // wave-uniform -> s_load
            acc[r] = fmaf(wr[0], h.x, acc[r]);
            acc[r] = fmaf(wr[1], h.y, acc[r]);
            acc[r] = fmaf(wr[2], h.z, acc[r]);
            acc[r] = fmaf(wr[3], h.w, acc[r]);
        }
    }

    __shared__ float red[4][6][64];
    #pragma unroll
    for (int r = 0; r < 6; ++r) red[wv][r][lane] = acc[r];
    __syncthreads();

    if (wv == 0) {
        float s[6];
        #pragma unroll
        for (int r = 0; r < 6; ++r)
            s[r] = red[0][r][lane] + red[1][r][lane] +
                   red[2][r][lane] + red[3][r][lane];
        float partial = 0.0f;
        #pragma unroll
        for (int u = 0; u < 2; ++u) {
            int j = j0 + u;
            float gi = s[u * 3 + 0] + b_ih2[j]        + b_hh2[j];
            float gg = s[u * 3 + 1] + b_ih2[1024 + j] + b_hh2[1024 + j];
            float go = s[u * 3 + 2] + b_ih2[1536 + j] + b_hh2[1536 + j];
            float c2 = sigmoidf_(gi) * tanhf(gg);
            float h2 = sigmoidf_(go) * tanhf(c2);
            partial  = fmaf(h2, W_lin[j], partial);
        }
        atomicAdd(out + bt, partial);
    }
}

// ---------------------------------------------------------------------------
extern "C" void kernel_launch(void* const* d_in, const int* in_sizes, int n_in,
                              void* d_out, int out_size, void* d_ws, size_t ws_size,
                              hipStream_t stream) {
    const float* input = (const float*)d_in[0];
    const float* z     = (const float*)d_in[1];
    // d_in[2]=h0, d_in[3]=c0 zeros -> unused; d_in[5]=W_hh1, d_in[9]=W_hh2 dead
    const float* W_ih1 = (const float*)d_in[4];
    const float* b_ih1 = (const float*)d_in[6];
    const float* b_hh1 = (const float*)d_in[7];
    const float* W_ih2 = (const float*)d_in[8];
    const float* b_ih2 = (const float*)d_in[10];
    const float* b_hh2 = (const float*)d_in[11];
    const float* W_lin = (const float*)d_in[12];
    const float* b_lin = (const float*)d_in[13];

    float* out  = (float*)d_out;            // 256 floats
    float* xin4 = (float*)d_ws;             // 24*256*4 floats (96 KB)
    float* h1p  = xin4 + 24 * NB * 4;       // 128*256*4 floats (512 KB)

    k_prep <<<  96, 256, 0, stream>>>(input, z, b_lin, xin4, out);
    k_lstm1<<<1024,  64, 0, stream>>>(W_ih1, b_ih1, b_hh1, xin4, h1p);
    k_lstm2<<<1024, 256, 0, stream>>>(W_ih2, b_ih2, b_hh2, W_lin, h1p, out);
}